// Round 4
// baseline (98.583 us; speedup 1.0000x reference)
//
#include <hip/hip_runtime.h>
#include <math.h>

#define NC 1024
#define NF 16384
#define NPTS (2*NF + 2*NC)   // 34816 packed points
#define TPB  256
#define NSLOT 8              // one max-plane per 2048-target column-block
#define LBLK (NPTS/256)      // 136 loss blocks, exactly 1 query/thread

typedef _Float16 f16x8 __attribute__((ext_vector_type(8)));
typedef float    f32x16 __attribute__((ext_vector_type(16)));

// VGPR-form MFMA via inline asm (prior rounds: __builtin path pins D/acc in
// AGPRs -> per-iter v_accvgpr traffic in the max-retire; "=&v" earlyclobber
// forces a VGPR dst; literal 0 C-operand is a legal inline constant).
// NOTE (R2 post-mortem): operand order is LOAD-BEARING. A=query-rec (a-pattern),
// B=target-rec (b-pattern). Swapping roles breaks numerics: the A and B
// fragment k-orderings of v_mfma_f32_32x32x16_f16 are NOT element-symmetric
// (measured: flip gave 0.335 p2p error while insensitive n2p still passed).
#define MFMA_V(d, a, b) \
    asm("v_mfma_f32_32x32x16_f16 %0, %1, %2, 0" : "=&v"(d) : "v"(a), "v"(b))

// Packed point-index layout (shared by mdv planes and the loss kernel):
//   [0, NF)            : ref_points_f             (pass A queries; pass B/D targets)
//   [NF, 2NF)          : src_points_f transformed (pass B queries; pass A/C targets)
//   [2NF, 2NF+NC)      : ref_points_c             (pass C queries)
//   [2NF+NC, 2NF+2NC)  : src_points_c transformed (pass D queries)
__device__ __forceinline__ void load_point(int idx,
    const float* __restrict__ refc, const float* __restrict__ srcc,
    const float* __restrict__ reff, const float* __restrict__ srcf,
    const float* __restrict__ T, float& x, float& y, float& z)
{
    const float* p; bool xf;
    if (idx < NF)           { p = reff + 3*idx;             xf = false; }
    else if (idx < 2*NF)    { p = srcf + 3*(idx - NF);      xf = true;  }
    else if (idx < 2*NF+NC) { p = refc + 3*(idx - 2*NF);    xf = false; }
    else                    { p = srcc + 3*(idx - 2*NF-NC); xf = true;  }
    x = p[0]; y = p[1]; z = p[2];
    if (xf) {   // expression identical to the verified prep_kernel
        float nx = T[0]*x + T[1]*y + T[2]*z  + T[3];
        float ny = T[4]*x + T[5]*y + T[6]*z  + T[7];
        float nz = T[8]*x + T[9]*y + T[10]*z + T[11];
        x = nx; y = ny; z = nz;
    }
}

__device__ __forceinline__ void split3(float x, float y, float z,
    _Float16& hx, _Float16& hy, _Float16& hz,
    _Float16& lx, _Float16& ly, _Float16& lz)
{
    hx = (_Float16)x; hy = (_Float16)y; hz = (_Float16)z;
    lx = (_Float16)(x - (float)hx);
    ly = (_Float16)(y - (float)hy);
    lz = (_Float16)(z - (float)hz);
}

// Fused MFMA min-distance kernel (R1/R3-verified core), 2-chunk variant:
// each block covers 2048 targets via two sequential 1024-record stagings
// into the same 32 KB LDS buffer, accumulating acc across both chunks.
// Halves block count (per-block prologue/epilogue) and NSLOT (loss reads).
//   sum_k A[k]B[k] = (qh+ql).(ph+pl) - h_p  (residual ~1e-5)
// Block = 256 query rows x 2048 targets. Grid 1088:
//   A [0,512):      rb in [0,64) x ck in [0,8)  Q=ref_f    T=src_f_t
//   B [512,1024):   same shape                   Q=src_f_t  T=ref_f
//   C [1024,1056):  rb in [0,4)  x ck in [0,8)  Q=ref_c    T=src_f_t
//   D [1056,1088):  same shape                   Q=src_c_t  T=ref_f
// Output: mdv[ck*NPTS + q] = max_t(q.t - h_t) - h_q over this ck's 2048
// targets. 8 ck-blocks per query write disjoint planes -> plain stores.
__global__ __launch_bounds__(TPB, 4) void minmax_kernel(
    const float* __restrict__ refc, const float* __restrict__ srcc,
    const float* __restrict__ reff, const float* __restrict__ srcf,
    const float* __restrict__ T, float* __restrict__ mdv,
    unsigned* __restrict__ counter)
{
    // 32KB staging (plane0 = 1024 b0-recs, plane1 = 1024 b1-recs);
    // reused after the final barrier as 4 x 8704B per-wave transpose scratch.
    __shared__ __align__(16) char ldsraw[34816];
    f16x8* sbuf = (f16x8*)ldsraw;

    // zero the loss ticket counter (stream order: minmax completes before loss)
    if (blockIdx.x == 0 && threadIdx.x == 0) *counter = 0u;

    int b = blockIdx.x;
    int qoff, toff, rb, ck;
    if (b < 512)       { rb = b >> 3;              ck = b & 7; qoff = 0;          toff = NF; }
    else if (b < 1024) { int bb=b-512;  rb=bb>>3;  ck=bb&7;    qoff = NF;         toff = 0;  }
    else if (b < 1056) { int bb=b-1024; rb=bb>>3;  ck=bb&7;    qoff = 2*NF;       toff = NF; }
    else               { int bb=b-1056; rb=bb>>3;  ck=bb&7;    qoff = 2*NF + NC;  toff = 0;  }
    int rbase = qoff + rb * 256;

    int tid = threadIdx.x, wv = tid >> 6, ln = tid & 63;
    int m  = ln & 31;        // A-row within tile / B-col (target) within tile
    int hf = ln >> 5;        // K-group select

    // Query A-fragments + half-norms, computed in-register (persist across chunks).
    f16x8 aA, aB; float hq0, hq1;
    {
        float x, y, z;
        load_point(rbase + wv*64 + m, refc, srcc, reff, srcf, T, x, y, z);
        hq0 = 0.5f*(x*x + y*y + z*z);
        _Float16 hx, hy, hz, lx, ly, lz;
        split3(x, y, z, hx, hy, hz, lx, ly, lz);
        _Float16 one = (_Float16)1.0f, zz = (_Float16)0.0f;
        aA = hf ? (f16x8){hz, one, one, lx, ly, lz, zz, zz}
                : (f16x8){hx, hy, hz, lx, ly, lz, hx, hy};
    }
    {
        float x, y, z;
        load_point(rbase + wv*64 + m + 32, refc, srcc, reff, srcf, T, x, y, z);
        hq1 = 0.5f*(x*x + y*y + z*z);
        _Float16 hx, hy, hz, lx, ly, lz;
        split3(x, y, z, hx, hy, hz, lx, ly, lz);
        _Float16 one = (_Float16)1.0f, zz = (_Float16)0.0f;
        aB = hf ? (f16x8){hz, one, one, lx, ly, lz, zz, zz}
                : (f16x8){hx, hy, hz, lx, ly, lz, hx, hy};
    }

    f32x16 acc0, acc1;
#pragma unroll
    for (int r = 0; r < 16; r++) { acc0[r] = -3.0e38f; acc1[r] = -3.0e38f; }

    for (int c = 0; c < 2; ++c) {
        if (c > 0) __syncthreads();    // all waves done reading previous chunk
        int tbase = toff + (ck * 2 + c) * 1024;

        // Stage 1024 target records (both K-group planes) from raw points.
#pragma unroll
        for (int k = 0; k < 4; k++) {
            int i = tid + k * 256;
            float x, y, z;
            load_point(tbase + i, refc, srcc, reff, srcf, T, x, y, z);
            float h = 0.5f*(x*x + y*y + z*z);
            _Float16 hx, hy, hz, lx, ly, lz;
            split3(x, y, z, hx, hy, hz, lx, ly, lz);
            _Float16 hh = (_Float16)h;
            _Float16 hl = (_Float16)(h - (float)hh);
            _Float16 zz = (_Float16)0.0f;
            sbuf[i]        = (f16x8){hx, hy, hz, hx, hy, hz, lx, ly};
            sbuf[1024 + i] = (f16x8){lz, (_Float16)(-hh), (_Float16)(-hl), lx, ly, lz, zz, zz};
        }

        __syncthreads();

        const f16x8* sb = sbuf + hf * 1024 + m;
        f16x8 bA = sb[0], bB = sb[32];
        for (int u = 0; u < 16; ++u) {            // 2 B-tiles (64 targets) per iter
            f32x16 d0, d1, d2, d3;
            MFMA_V(d0, aA, bA);
            MFMA_V(d1, aA, bB);
            MFMA_V(d2, aB, bA);
            MFMA_V(d3, aB, bB);
            if (u < 15) {                          // prefetch under the MFMAs
                bA = sb[(u + 1) * 64];
                bB = sb[(u + 1) * 64 + 32];
            }
#pragma unroll
            for (int r = 0; r < 16; r++)
                acc0[r] = fmaxf(fmaxf(acc0[r], d0[r]), d1[r]);   // -> v_max3_f32
#pragma unroll
            for (int r = 0; r < 16; r++)
                acc1[r] = fmaxf(fmaxf(acc1[r], d2[r]), d3[r]);
        }
    }

    __syncthreads();   // all waves done reading sbuf before scratch overwrite

    // Col-reduce via per-wave LDS transpose (wave-private scratch, no barrier).
    // C/D layout: col=lane&31, row=(r&3)+8*(r>>2)+4*hf.  Row stride 34 floats:
    // writes (2row+m)%32 conflict-free; float2 reads 2-way (free).
    float* scr = (float*)(ldsraw + wv * 8704);     // 64 rows x 34 floats
#pragma unroll
    for (int r = 0; r < 16; r++) {
        int row = (r & 3) + 8 * (r >> 2) + 4 * hf;
        scr[row * 34 + m]        = acc0[r];
        scr[(row + 32) * 34 + m] = acc1[r];
    }
    __builtin_amdgcn_s_waitcnt(0);   // own-wave LDS writes visible

    const float2* rv = (const float2*)(ldsraw + wv * 8704 + ln * 136);
    float mx = -3.0e38f;
#pragma unroll
    for (int k = 0; k < 16; k += 2) {
        float2 v0 = rv[k], v1 = rv[k + 1];
        mx = fmaxf(fmaxf(mx, fmaxf(v0.x, v0.y)), fmaxf(v1.x, v1.y));
    }

    // h_q for the row this lane stores (query wv*64+ln): held as hq0 by lane
    // ln&31 (rows 0-31) / hq1 by lane ln&31 (rows 32-63). Two shuffles + select.
    float g0 = __shfl(hq0, ln & 31, 64);
    float g1 = __shfl(hq1, ln & 31, 64);
    float hq = (ln < 32) ? g0 : g1;

    mdv[ck * NPTS + rbase + wv * 64 + ln] = mx - hq;   // plain store, disjoint
}

// Loss: 136 blocks x 256 threads = exactly one query-eval per thread.
// Blocks [0,128): p2p (32768 elems, thr=0.1).  Blocks [128,136): n2p (thr=0.5).
// mdv already folds -h_q, so gt is just max_plane > -thr^2/2.
// Last-finishing block (device-scope ticket, R3-validated) does the
// deterministic finalize and resets the counter (idempotent across replays).
__global__ __launch_bounds__(256) void loss_partial(
    const float* __restrict__ mdv,
    const float* __restrict__ p2p_ref, const float* __restrict__ p2p_src,
    const float* __restrict__ n2p_ref, const float* __restrict__ n2p_src,
    float* __restrict__ part, unsigned* __restrict__ counter,
    float* __restrict__ out)
{
    __shared__ float rc[4], rp[4], rn[4];
    __shared__ unsigned ticket_s;
    int gi = blockIdx.x * 256 + threadIdx.x;   // 0..34815

    float score; int qi; float thr_half;
    if (gi < 2*NF) {                                   // p2p
        thr_half = 0.5f * (0.1f * 0.1f);
        if (gi < NF) { score = p2p_src[gi];      qi = NF + gi; }       // src_gt: pass B
        else         { score = p2p_ref[gi - NF]; qi = gi - NF; }       // ref_gt: pass A
    } else {                                           // n2p
        thr_half = 0.5f * (0.5f * 0.5f);
        int i = gi - 2*NF;
        if (i < NC) { score = n2p_src[i];      qi = 2*NF + NC + i; }   // src_gt_n: pass D
        else        { score = n2p_ref[i - NC]; qi = 2*NF + (i - NC); } // ref_gt_n: pass C
    }

    float v = mdv[qi];
#pragma unroll
    for (int s = 1; s < NSLOT; s++)
        v = fmaxf(v, mdv[s * NPTS + qi]);              // coalesced plane reads

    bool g = v > -thr_half;                            // min dist^2 < thr^2
    float cnt  = g ? 1.0f : 0.0f;
    float spos = g ? -logf(score) : 0.0f;
    float sneg = g ? 0.0f : -log1pf(-score);

    int lane = threadIdx.x & 63, wid = threadIdx.x >> 6;
#pragma unroll
    for (int off = 32; off > 0; off >>= 1) {
        cnt  += __shfl_down(cnt,  off, 64);
        spos += __shfl_down(spos, off, 64);
        sneg += __shfl_down(sneg, off, 64);
    }
    if (lane == 0) { rc[wid] = cnt; rp[wid] = spos; rn[wid] = sneg; }
    __syncthreads();
    if (threadIdx.x == 0) {
        part[blockIdx.x * 3 + 0] = rc[0] + rc[1] + rc[2] + rc[3];
        part[blockIdx.x * 3 + 1] = rp[0] + rp[1] + rp[2] + rp[3];
        part[blockIdx.x * 3 + 2] = rn[0] + rn[1] + rn[2] + rn[3];
        __threadfence();                               // release part stores
        ticket_s = atomicAdd(counter, 1u);             // device-scope
    }
    __syncthreads();

    if (ticket_s == LBLK - 1) {                        // last block finalizes
        __threadfence();                               // acquire others' parts
        int ln = threadIdx.x;
        if (ln < 64) {
            // p2p: blocks ln and ln+64
            float c  = part[ln*3]     + part[(ln+64)*3];
            float sp = part[ln*3 + 1] + part[(ln+64)*3 + 1];
            float sn = part[ln*3 + 2] + part[(ln+64)*3 + 2];
            // n2p: blocks 128..135 on lanes 0..7
            float cn = 0.0f, spn = 0.0f, snn = 0.0f;
            if (ln < 8) {
                cn  = part[(128+ln)*3];
                spn = part[(128+ln)*3 + 1];
                snn = part[(128+ln)*3 + 2];
            }
#pragma unroll
            for (int off = 32; off > 0; off >>= 1) {
                c   += __shfl_down(c,   off, 64);
                sp  += __shfl_down(sp,  off, 64);
                sn  += __shfl_down(sn,  off, 64);
                cn  += __shfl_down(cn,  off, 64);
                spn += __shfl_down(spn, off, 64);
                snn += __shfl_down(snn, off, 64);
            }
            if (ln == 0) {
                float Np = 2.0f * NF;
                float wneg = c / Np, wpos = 1.0f - wneg;
                out[1] = (wpos * sp + wneg * sn) / Np;          // p2p
                float Nn = 2.0f * NC;
                float wnegn = cn / Nn, wposn = 1.0f - wnegn;
                out[0] = (wposn * spn + wnegn * snn) / Nn;      // n2p
                *counter = 0u;                                  // re-arm
            }
        }
    }
}

extern "C" void kernel_launch(void* const* d_in, const int* in_sizes, int n_in,
                              void* d_out, int out_size, void* d_ws, size_t ws_size,
                              hipStream_t stream) {
    (void)in_sizes; (void)n_in; (void)out_size; (void)ws_size;
    const float* refc = (const float*)d_in[0];
    const float* srcc = (const float*)d_in[1];
    const float* reff = (const float*)d_in[2];
    const float* srcf = (const float*)d_in[3];
    const float* T    = (const float*)d_in[4];
    const float* p2p_ref = (const float*)d_in[5];
    const float* p2p_src = (const float*)d_in[6];
    const float* n2p_ref = (const float*)d_in[7];
    const float* n2p_src = (const float*)d_in[8];
    float* out = (float*)d_out;

    float* mdv      = (float*)d_ws;            // 8 * 34816 floats = 1.11 MB
    float* part     = mdv + NSLOT * NPTS;      // 136 * 3 floats
    unsigned* cntr  = (unsigned*)(part + 3 * LBLK);

    minmax_kernel<<<1088, TPB, 0, stream>>>(refc, srcc, reff, srcf, T, mdv, cntr);
    loss_partial<<<LBLK, 256, 0, stream>>>(mdv, p2p_ref, p2p_src,
                                           n2p_ref, n2p_src, part, cntr, out);
}

// Round 5
// 93.661 us; speedup vs baseline: 1.0526x; 1.0526x over previous
//
#include <hip/hip_runtime.h>
#include <math.h>

#define NC 1024
#define NF 16384
#define NPTS (2*NF + 2*NC)   // 34816 packed points
#define TPB  256
#define NSLOT 16             // one max-plane per ck column-block
#define LBLK (NPTS/256)      // 136 loss blocks, exactly 1 query/thread

typedef _Float16 f16x8 __attribute__((ext_vector_type(8)));
typedef float    f32x16 __attribute__((ext_vector_type(16)));

// VGPR-form MFMA via inline asm (prior rounds: __builtin path pins D/acc in
// AGPRs -> per-iter v_accvgpr traffic in the max-retire; "=&v" earlyclobber
// forces a VGPR dst; literal 0 C-operand is a legal inline constant).
// NOTE (R2 post-mortem): operand order is LOAD-BEARING. A=query-rec (a-pattern),
// B=target-rec (b-pattern). Swapping roles breaks numerics: the A and B
// fragment k-orderings of v_mfma_f32_32x32x16_f16 are NOT element-symmetric.
#define MFMA_V(d, a, b) \
    asm("v_mfma_f32_32x32x16_f16 %0, %1, %2, 0" : "=&v"(d) : "v"(a), "v"(b))

// Packed point-index layout (shared by mdv planes and the loss kernel):
//   [0, NF)            : ref_points_f             (pass A queries; pass B/D targets)
//   [NF, 2NF)          : src_points_f transformed (pass B queries; pass A/C targets)
//   [2NF, 2NF+NC)      : ref_points_c             (pass C queries)
//   [2NF+NC, 2NF+2NC)  : src_points_c transformed (pass D queries)
__device__ __forceinline__ void load_point(int idx,
    const float* __restrict__ refc, const float* __restrict__ srcc,
    const float* __restrict__ reff, const float* __restrict__ srcf,
    const float* __restrict__ T, float& x, float& y, float& z)
{
    const float* p; bool xf;
    if (idx < NF)           { p = reff + 3*idx;             xf = false; }
    else if (idx < 2*NF)    { p = srcf + 3*(idx - NF);      xf = true;  }
    else if (idx < 2*NF+NC) { p = refc + 3*(idx - 2*NF);    xf = false; }
    else                    { p = srcc + 3*(idx - 2*NF-NC); xf = true;  }
    x = p[0]; y = p[1]; z = p[2];
    if (xf) {   // expression identical to the verified prep_kernel
        float nx = T[0]*x + T[1]*y + T[2]*z  + T[3];
        float ny = T[4]*x + T[5]*y + T[6]*z  + T[7];
        float nz = T[8]*x + T[9]*y + T[10]*z + T[11];
        x = nx; y = ny; z = nz;
    }
}

__device__ __forceinline__ void split3(float x, float y, float z,
    _Float16& hx, _Float16& hy, _Float16& hz,
    _Float16& lx, _Float16& ly, _Float16& lz)
{
    hx = (_Float16)x; hy = (_Float16)y; hz = (_Float16)z;
    lx = (_Float16)(x - (float)hx);
    ly = (_Float16)(y - (float)hy);
    lz = (_Float16)(z - (float)hz);
}

// Fused MFMA min-distance kernel (best-measured structure, 96.36us, absmax 0):
// computes f16 hi/lo split records IN-BLOCK from raw points.
//   sum_k A[k]B[k] = (qh+ql).(ph+pl) - h_p  (residual ~1e-5)
// Block = 256 query rows x 1024 targets. Grid 2176:
//   A [0,1024):     rb in [0,64) x ck in [0,16)  Q=ref_f    T=src_f_t
//   B [1024,2048):  same shape                    Q=src_f_t  T=ref_f
//   C [2048,2112):  rb in [0,4)  x ck in [0,16)  Q=ref_c    T=src_f_t
//   D [2112,2176):  same shape                    Q=src_c_t  T=ref_f
// Output: mmv[ck*NPTS + row] = per-row max of (q.t - h_t) over this ck's 1024
// targets. 16 ck-blocks per row write disjoint planes -> plain stores, no
// atomics, no init.
// R4 lesson: do NOT merge target-chunks into one block (mid-block restage
// barrier bubbles don't hide across synchronized co-resident blocks; +2us).
__global__ __launch_bounds__(TPB, 4) void minmax_kernel(
    const float* __restrict__ refc, const float* __restrict__ srcc,
    const float* __restrict__ reff, const float* __restrict__ srcf,
    const float* __restrict__ T, float* __restrict__ mmv)
{
    // 32KB staging (plane0 = 1024 b0-recs, plane1 = 1024 b1-recs);
    // reused after barrier as 4 x 8704B per-wave transpose scratch.
    __shared__ __align__(16) char ldsraw[34816];
    f16x8* sbuf = (f16x8*)ldsraw;

    int b = blockIdx.x;
    int qoff, toff, rb, ck;
    if (b < 1024)      { rb = b >> 4;              ck = b & 15; qoff = 0;          toff = NF; }
    else if (b < 2048) { int bb=b-1024; rb=bb>>4;  ck=bb&15;    qoff = NF;         toff = 0;  }
    else if (b < 2112) { int bb=b-2048; rb=bb>>4;  ck=bb&15;    qoff = 2*NF;       toff = NF; }
    else               { int bb=b-2112; rb=bb>>4;  ck=bb&15;    qoff = 2*NF + NC;  toff = 0;  }
    int rbase = qoff + rb * 256;
    int tbase = toff + ck * 1024;

    int tid = threadIdx.x, wv = tid >> 6, ln = tid & 63;
    int m  = ln & 31;        // A-row within tile / B-col (target) within tile
    int hf = ln >> 5;        // K-group select

    // Stage 1024 target records (both K-group planes) from raw points.
#pragma unroll
    for (int k = 0; k < 4; k++) {
        int i = tid + k * 256;
        float x, y, z;
        load_point(tbase + i, refc, srcc, reff, srcf, T, x, y, z);
        float h = 0.5f*(x*x + y*y + z*z);
        _Float16 hx, hy, hz, lx, ly, lz;
        split3(x, y, z, hx, hy, hz, lx, ly, lz);
        _Float16 hh = (_Float16)h;
        _Float16 hl = (_Float16)(h - (float)hh);
        _Float16 zz = (_Float16)0.0f;
        sbuf[i]        = (f16x8){hx, hy, hz, hx, hy, hz, lx, ly};
        sbuf[1024 + i] = (f16x8){lz, (_Float16)(-hh), (_Float16)(-hl), lx, ly, lz, zz, zz};
    }

    // Query A-fragments, computed in-register.
    f16x8 aA, aB;
    {
        float x, y, z;
        load_point(rbase + wv*64 + m, refc, srcc, reff, srcf, T, x, y, z);
        _Float16 hx, hy, hz, lx, ly, lz;
        split3(x, y, z, hx, hy, hz, lx, ly, lz);
        _Float16 one = (_Float16)1.0f, zz = (_Float16)0.0f;
        aA = hf ? (f16x8){hz, one, one, lx, ly, lz, zz, zz}
                : (f16x8){hx, hy, hz, lx, ly, lz, hx, hy};
    }
    {
        float x, y, z;
        load_point(rbase + wv*64 + m + 32, refc, srcc, reff, srcf, T, x, y, z);
        _Float16 hx, hy, hz, lx, ly, lz;
        split3(x, y, z, hx, hy, hz, lx, ly, lz);
        _Float16 one = (_Float16)1.0f, zz = (_Float16)0.0f;
        aB = hf ? (f16x8){hz, one, one, lx, ly, lz, zz, zz}
                : (f16x8){hx, hy, hz, lx, ly, lz, hx, hy};
    }

    f32x16 acc0, acc1;
#pragma unroll
    for (int r = 0; r < 16; r++) { acc0[r] = -3.0e38f; acc1[r] = -3.0e38f; }

    __syncthreads();

    const f16x8* sb = sbuf + hf * 1024 + m;
    f16x8 bA = sb[0], bB = sb[32];
    for (int u = 0; u < 16; ++u) {            // 2 B-tiles (64 targets) per iter
        f32x16 d0, d1, d2, d3;
        MFMA_V(d0, aA, bA);
        MFMA_V(d1, aA, bB);
        MFMA_V(d2, aB, bA);
        MFMA_V(d3, aB, bB);
        if (u < 15) {                          // prefetch under the MFMAs
            bA = sb[(u + 1) * 64];
            bB = sb[(u + 1) * 64 + 32];
        }
#pragma unroll
        for (int r = 0; r < 16; r++)
            acc0[r] = fmaxf(fmaxf(acc0[r], d0[r]), d1[r]);   // -> v_max3_f32
#pragma unroll
        for (int r = 0; r < 16; r++)
            acc1[r] = fmaxf(fmaxf(acc1[r], d2[r]), d3[r]);
    }

    __syncthreads();   // all waves done reading sbuf before scratch overwrite

    // Col-reduce via per-wave LDS transpose (wave-private scratch, no barrier).
    // C/D layout: col=lane&31, row=(r&3)+8*(r>>2)+4*hf.  Row stride 34 floats:
    // writes (2row+m)%32 conflict-free; float2 reads 2-way (free).
    float* scr = (float*)(ldsraw + wv * 8704);     // 64 rows x 34 floats
#pragma unroll
    for (int r = 0; r < 16; r++) {
        int row = (r & 3) + 8 * (r >> 2) + 4 * hf;
        scr[row * 34 + m]        = acc0[r];
        scr[(row + 32) * 34 + m] = acc1[r];
    }
    __builtin_amdgcn_s_waitcnt(0);   // own-wave LDS writes visible

    const float2* rv = (const float2*)(ldsraw + wv * 8704 + ln * 136);
    float mx = -3.0e38f;
#pragma unroll
    for (int k = 0; k < 16; k += 2) {
        float2 v0 = rv[k], v1 = rv[k + 1];
        mx = fmaxf(fmaxf(mx, fmaxf(v0.x, v0.y)), fmaxf(v1.x, v1.y));
    }
    mmv[ck * NPTS + rbase + wv * 64 + ln] = mx;   // plain store, disjoint slots
}

// Loss partials: 136 blocks x 256 threads = exactly one query-eval per thread.
// Blocks [0,128): p2p (32768 elems, thr=0.1).  Blocks [128,136): n2p (thr=0.5).
// Each thread reduces the 16 mmv planes, computes h_q from raw points inline.
__global__ __launch_bounds__(256) void loss_partial(
    const float* __restrict__ mmv,
    const float* __restrict__ refc, const float* __restrict__ srcc,
    const float* __restrict__ reff, const float* __restrict__ srcf,
    const float* __restrict__ T,
    const float* __restrict__ p2p_ref, const float* __restrict__ p2p_src,
    const float* __restrict__ n2p_ref, const float* __restrict__ n2p_src,
    float* __restrict__ part)
{
    __shared__ float rc[4], rp[4], rn[4];
    int gi = blockIdx.x * 256 + threadIdx.x;   // 0..34815

    float score; int qi; float thr_half;
    if (gi < 2*NF) {                                   // p2p
        thr_half = 0.5f * (0.1f * 0.1f);
        if (gi < NF) { score = p2p_src[gi];      qi = NF + gi; }       // src_gt: pass B
        else         { score = p2p_ref[gi - NF]; qi = gi - NF; }       // ref_gt: pass A
    } else {                                           // n2p
        thr_half = 0.5f * (0.5f * 0.5f);
        int i = gi - 2*NF;
        if (i < NC) { score = n2p_src[i];      qi = 2*NF + NC + i; }   // src_gt_n: pass D
        else        { score = n2p_ref[i - NC]; qi = 2*NF + (i - NC); } // ref_gt_n: pass C
    }

    float maxm = mmv[qi];
#pragma unroll
    for (int s = 1; s < NSLOT; s++)
        maxm = fmaxf(maxm, mmv[s * NPTS + qi]);        // coalesced plane reads

    float x, y, z;
    load_point(qi, refc, srcc, reff, srcf, T, x, y, z);
    float hq = 0.5f*(x*x + y*y + z*z);                 // |q|^2/2, fp32 exact

    bool g = maxm > (hq - thr_half);                   // min dist^2 < thr^2
    float cnt  = g ? 1.0f : 0.0f;
    float spos = g ? -logf(score) : 0.0f;
    float sneg = g ? 0.0f : -log1pf(-score);

    int lane = threadIdx.x & 63, wid = threadIdx.x >> 6;
#pragma unroll
    for (int off = 32; off > 0; off >>= 1) {
        cnt  += __shfl_down(cnt,  off, 64);
        spos += __shfl_down(spos, off, 64);
        sneg += __shfl_down(sneg, off, 64);
    }
    if (lane == 0) { rc[wid] = cnt; rp[wid] = spos; rn[wid] = sneg; }
    __syncthreads();
    if (threadIdx.x == 0) {
        part[blockIdx.x * 3 + 0] = rc[0] + rc[1] + rc[2] + rc[3];
        part[blockIdx.x * 3 + 1] = rp[0] + rp[1] + rp[2] + rp[3];
        part[blockIdx.x * 3 + 2] = rn[0] + rn[1] + rn[2] + rn[3];
    }
}

// 1-block finalize: deterministic fixed-order reduction of the 136 partials.
__global__ __launch_bounds__(64) void finalize_kernel(
    const float* __restrict__ part, float* __restrict__ out)
{
    int ln = threadIdx.x;
    // p2p: blocks ln and ln+64
    float c  = part[ln*3]     + part[(ln+64)*3];
    float sp = part[ln*3 + 1] + part[(ln+64)*3 + 1];
    float sn = part[ln*3 + 2] + part[(ln+64)*3 + 2];
    // n2p: blocks 128..135 on lanes 0..7
    float cn = 0.0f, spn = 0.0f, snn = 0.0f;
    if (ln < 8) {
        cn  = part[(128+ln)*3];
        spn = part[(128+ln)*3 + 1];
        snn = part[(128+ln)*3 + 2];
    }
#pragma unroll
    for (int off = 32; off > 0; off >>= 1) {
        c   += __shfl_down(c,   off, 64);
        sp  += __shfl_down(sp,  off, 64);
        sn  += __shfl_down(sn,  off, 64);
        cn  += __shfl_down(cn,  off, 64);
        spn += __shfl_down(spn, off, 64);
        snn += __shfl_down(snn, off, 64);
    }
    if (ln == 0) {
        float Np = 2.0f * NF;
        float wneg = c / Np, wpos = 1.0f - wneg;
        out[1] = (wpos * sp + wneg * sn) / Np;          // p2p
        float Nn = 2.0f * NC;
        float wnegn = cn / Nn, wposn = 1.0f - wnegn;
        out[0] = (wposn * spn + wnegn * snn) / Nn;      // n2p
    }
}

extern "C" void kernel_launch(void* const* d_in, const int* in_sizes, int n_in,
                              void* d_out, int out_size, void* d_ws, size_t ws_size,
                              hipStream_t stream) {
    (void)in_sizes; (void)n_in; (void)out_size; (void)ws_size;
    const float* refc = (const float*)d_in[0];
    const float* srcc = (const float*)d_in[1];
    const float* reff = (const float*)d_in[2];
    const float* srcf = (const float*)d_in[3];
    const float* T    = (const float*)d_in[4];
    const float* p2p_ref = (const float*)d_in[5];
    const float* p2p_src = (const float*)d_in[6];
    const float* n2p_ref = (const float*)d_in[7];
    const float* n2p_src = (const float*)d_in[8];
    float* out = (float*)d_out;

    float* mmv  = (float*)d_ws;            // 16 * 34816 floats = 2.23 MB
    float* part = mmv + NSLOT * NPTS;      // 136 * 3 floats

    minmax_kernel<<<2176, TPB, 0, stream>>>(refc, srcc, reff, srcf, T, mmv);
    loss_partial<<<LBLK, 256, 0, stream>>>(mmv, refc, srcc, reff, srcf, T,
                                           p2p_ref, p2p_src, n2p_ref, n2p_src, part);
    finalize_kernel<<<1, 64, 0, stream>>>(part, out);
}